// Round 10
// baseline (182.186 us; speedup 1.0000x reference)
//
#include <hip/hip_runtime.h>
#include <hip/hip_bf16.h>

typedef __bf16 bf16;
typedef __attribute__((ext_vector_type(8))) __bf16 bf16x8;
typedef __attribute__((ext_vector_type(4))) float f32x4;

#define MFMA16(a, b, c) __builtin_amdgcn_mfma_f32_16x16x32_bf16(a, b, c, 0, 0, 0)
// async global->LDS, 16B per lane; LDS dest = wave-uniform base + lane*16
#define GLL16(gp, lp)                                                          \
  __builtin_amdgcn_global_load_lds(                                            \
      (const __attribute__((address_space(1))) void*)(gp),                     \
      (__attribute__((address_space(3))) void*)(lp), 16, 0, 0)

constexpr int Bsz = 2, Pseq = 2048, Mdim = 1024, NH = 16, Dh = 64;
constexpr int ROWS = Bsz * Pseq; // 4096
constexpr float LOG2E = 1.4426950408889634f;
constexpr float BIG_NEG = -3.0e38f;
constexpr float M0 = 8.0f; // fixed softmax max (log2 domain); scores bounded << 8

// ---------------- fused pre-pass: x cvt + both weight transposes ------------
__global__ __launch_bounds__(256) void k_pre(const float* __restrict__ X,
                                             bf16* __restrict__ Xb,
                                             const float* __restrict__ Wa,
                                             bf16* __restrict__ Wat,
                                             const float* __restrict__ Wp,
                                             bf16* __restrict__ Wpt) {
  __shared__ __align__(16) bf16 tile[64][72];
  int blk = blockIdx.x;
  int t = threadIdx.x;
  if (blk < 1024) {
    const f32x4* X4 = (const f32x4*)X;
    int i0 = blk * 1024 + t; // 1024 blocks x 4 chunks x 256 threads = 2^20 float4s
#pragma unroll
    for (int c = 0; c < 4; ++c) {
      int i = i0 + c * 256;
      f32x4 v = X4[i];
      union { bf16 h[4]; uint2 u; } pk;
      pk.h[0] = (bf16)v[0]; pk.h[1] = (bf16)v[1];
      pk.h[2] = (bf16)v[2]; pk.h[3] = (bf16)v[3];
      ((uint2*)Xb)[i] = pk.u;
    }
    return;
  }
  const float* W; bf16* Wt; int Ndim, n0, k0;
  if (blk < 1792) {
    int bx = blk - 1024; // 48 n-tiles x 16 k-tiles
    W = Wa; Wt = Wat; Ndim = 3 * Mdim;
    n0 = (bx % 48) * 64; k0 = (bx / 48) * 64;
  } else {
    int bx = blk - 1792; // 16 x 16
    W = Wp; Wt = Wpt; Ndim = Mdim;
    n0 = (bx & 15) * 64; k0 = (bx >> 4) * 64;
  }
  int tc = t & 15, tr = t >> 4;
#pragma unroll
  for (int pass = 0; pass < 4; ++pass) {
    int r = tr + pass * 16;
    f32x4 v = *(const f32x4*)(W + (size_t)(k0 + r) * Ndim + n0 + tc * 4);
#pragma unroll
    for (int i = 0; i < 4; ++i) tile[tc * 4 + i][r] = (bf16)v[i];
  }
  __syncthreads();
#pragma unroll
  for (int pass = 0; pass < 4; ++pass) {
    int n = tr + pass * 16;
    union { bf16 h[4]; uint2 u; } pk;
#pragma unroll
    for (int i = 0; i < 4; ++i) pk.h[i] = tile[n][tc * 4 + i];
    *(uint2*)(Wt + (size_t)(n0 + n) * Mdim + k0 + tc * 4) = pk.u;
  }
}

// -------- r5-proven GEMM core, generalized: C(TM x TN) = A[M][K].Bt[N][K]^T --
// BK=64, single-buffered (measured best at 3-4 blocks/CU, K=1024: r5=44us vs
// BK=32=51us, dbuf=60us). 2x2 waves, wave covers TM/2 x TN/2. XOR-swizzled
// 16B granules (key row&7) -> staging + b128 reads conflict-free.
template <int TM, int TN>
__device__ __forceinline__ void gemm_core(const bf16* __restrict__ A,
                                          const bf16* __restrict__ Bt,
                                          bf16* Ash, bf16* Bsh, int K,
                                          int row0, int col0,
                                          f32x4 (&acc)[TM / 32][TN / 32]) {
  constexpr int MT = TM / 32, NT = TN / 32;
  int tid = threadIdx.x;
  int lane = tid & 63, w = tid >> 6;
  int l15 = lane & 15, g = lane >> 4, l7 = lane & 7, l8 = lane >> 3;
  int wm = w & 1, wn = w >> 1;
  const bf16* Ag = A + (size_t)(row0 + w * 8 + l8) * K + (l7 ^ l8) * 8;
  const bf16* Bg = Bt + (size_t)(col0 + w * 8 + l8) * K + (l7 ^ l8) * 8;
  bf16* Asb = Ash + w * 512;
  bf16* Bsb = Bsh + w * 512;
  for (int k0 = 0; k0 < K; k0 += 64) {
#pragma unroll
    for (int p = 0; p < MT; ++p)
      GLL16(Ag + (size_t)(p * 32) * K + k0, Asb + p * 2048);
#pragma unroll
    for (int p = 0; p < NT; ++p)
      GLL16(Bg + (size_t)(p * 32) * K + k0, Bsb + p * 2048);
    __syncthreads();
#pragma unroll
    for (int ks = 0; ks < 2; ++ks) {
      int swz = ((ks * 4 + g) ^ l7) * 8;
      bf16x8 af[MT], bfr[NT];
#pragma unroll
      for (int mt = 0; mt < MT; ++mt)
        af[mt] = *(const bf16x8*)(Ash + (wm * (TM / 2) + mt * 16 + l15) * 64 + swz);
#pragma unroll
      for (int nt = 0; nt < NT; ++nt)
        bfr[nt] = *(const bf16x8*)(Bsh + (wn * (TN / 2) + nt * 16 + l15) * 64 + swz);
#pragma unroll
      for (int mt = 0; mt < MT; ++mt)
#pragma unroll
        for (int nt = 0; nt < NT; ++nt)
          acc[mt][nt] = MFMA16(af[mt], bfr[nt], acc[mt][nt]);
    }
    __syncthreads();
  }
}

// ---------------- QKV GEMM -> Q (pre-scaled by log2e/8), K [B,H,P,D]; V [B,H,D,P]
__global__ __launch_bounds__(256) void k_qkv(const bf16* __restrict__ Xb,
                                             const bf16* __restrict__ Wt,
                                             const float* __restrict__ bias,
                                             bf16* __restrict__ Qo,
                                             bf16* __restrict__ Ko,
                                             bf16* __restrict__ Vto) {
  __shared__ __align__(16) bf16 Ash[128 * 64], Bsh[128 * 64]; // 32 KB
  int cb = blockIdx.x, rb = blockIdx.y;
  int row0 = rb * 128, col0 = cb * 128;
  f32x4 acc[4][4];
  const f32x4 zero = {0.f, 0.f, 0.f, 0.f};
#pragma unroll
  for (int mt = 0; mt < 4; ++mt)
#pragma unroll
    for (int nt = 0; nt < 4; ++nt) acc[mt][nt] = zero;
  gemm_core<128, 128>(Xb, Wt, Ash, Bsh, Mdim, row0, col0, acc);

  int lane = threadIdx.x & 63, w = threadIdx.x >> 6;
  int l15 = lane & 15, g = lane >> 4;
  int wm = w & 1, wn = w >> 1;
  int sec = cb >> 3; // 0=q 1=k 2=v (uniform per block)
  if (sec < 2) {
    bf16* out = sec == 0 ? Qo : Ko;
    float scale = sec == 0 ? (0.125f * LOG2E) : 1.0f; // q/sqrt(64), log2 domain
#pragma unroll
    for (int nt = 0; nt < 4; ++nt) {
      int col = col0 + wn * 64 + nt * 16 + l15;
      int cm = col & 1023;
      int h = cm >> 6, d = cm & 63;
      float bv = bias[col];
#pragma unroll
      for (int mt = 0; mt < 4; ++mt)
#pragma unroll
        for (int r = 0; r < 4; ++r) {
          int row = row0 + wm * 64 + mt * 16 + g * 4 + r;
          int b = row >> 11, p = row & 2047;
          out[(size_t)((b * NH + h) * Pseq + p) * Dh + d] =
              (bf16)((acc[mt][nt][r] + bv) * scale);
        }
    }
  } else {
#pragma unroll
    for (int nt = 0; nt < 4; ++nt) {
      int col = col0 + wn * 64 + nt * 16 + l15;
      int cm = col & 1023;
      int h = cm >> 6, d = cm & 63;
      float bv = bias[col];
#pragma unroll
      for (int mt = 0; mt < 4; ++mt) {
        int row = row0 + wm * 64 + mt * 16 + g * 4;
        int b = row >> 11, p = row & 2047;
        union { bf16 hh[4]; uint2 u; } pk;
#pragma unroll
        for (int r = 0; r < 4; ++r) pk.hh[r] = (bf16)(acc[mt][nt][r] + bv);
        *(uint2*)(Vto + ((size_t)((b * NH + h) * Dh + d)) * Pseq + p) = pk.u;
      }
    }
  }
}

// ---------------- causal flash attention v2: 128-q blocks, 32 q/wave ---------
// Q,K [B,H,P,D] (Q pre-scaled log2e/8); Vt [B,H,D,P]; Z [B,P,M].
// Each K/V fragment read from LDS feeds 2 MFMAs (2 q-subtiles) -> LDS
// cyc/FLOP ~1.8x better than 16q/wave. 512 blocks = 2/CU; y->qt pairing
// makes every CU's two blocks sum to exactly 34 kv-iters. Staging dbuf,
// swizzles, fixed-max softmax identical to r5 (proven).
__global__ __launch_bounds__(256, 2) void k_attn(const bf16* __restrict__ Q,
                                                 const bf16* __restrict__ K,
                                                 const bf16* __restrict__ Vt,
                                                 bf16* __restrict__ Z) {
  __shared__ __align__(16) bf16 Ksh[2 * 64 * 64]; // 16 KB dbuf [buf][kv][d]
  __shared__ __align__(16) bf16 Vsh[2 * 64 * 64]; // 16 KB dbuf [buf][d][kv]
  __shared__ __align__(16) bf16 Pb[4 * 32 * 64];  // 16 KB, per-wave P (32q x 64kv)
  int bh = blockIdx.x;
  int y = blockIdx.y;
  int qt = (y < 8) ? y : 23 - y; // CU gets y and y+8 -> iters (2qt+2) sum to 34
  int b = bh >> 4, h = bh & 15;
  const bf16* Qb = Q + (size_t)bh * Pseq * Dh;
  const bf16* Kb = K + (size_t)bh * Pseq * Dh;
  const bf16* Vb = Vt + (size_t)bh * Dh * Pseq;
  int tid = threadIdx.x;
  int lane = tid & 63, w = tid >> 6;
  int l15 = lane & 15, g = lane >> 4, l7 = lane & 7;
  int q0 = qt * 128;
  int qw = q0 + w * 32; // wave's 32-q strip
  int njt = 2 * qt + 2; // kv64 tiles covering [0, q0+128)

  // Q B-fragments: qs-subtile q = qw + qs*16 + l15, k = ks*32 + g*8
  bf16x8 qf[2][2];
#pragma unroll
  for (int qs = 0; qs < 2; ++qs)
#pragma unroll
    for (int ks = 0; ks < 2; ++ks)
      qf[qs][ks] = *(const bf16x8*)(Qb + (size_t)(qw + qs * 16 + l15) * Dh + ks * 32 + g * 8);

  f32x4 O[2][4];
  const f32x4 zero = {0.f, 0.f, 0.f, 0.f};
#pragma unroll
  for (int qs = 0; qs < 2; ++qs)
#pragma unroll
    for (int nt = 0; nt < 4; ++nt) O[qs][nt] = zero;
  float lacc[2][4] = {{0.f, 0.f, 0.f, 0.f}, {0.f, 0.f, 0.f, 0.f}};

  int srow = tid >> 3;
  int sgr = (tid & 7) ^ (srow & 7);
  const bf16* Kgs = Kb + (size_t)srow * Dh + sgr * 8;
  const bf16* Vgs = Vb + (size_t)srow * Pseq + sgr * 8;
  bf16* Pw = Pb + w * 2048; // 32 x 64
  int pwr[2][4], prd[2];
#pragma unroll
  for (int qs = 0; qs < 2; ++qs)
#pragma unroll
    for (int mtl = 0; mtl < 4; ++mtl)
      pwr[qs][mtl] = (qs * 16 + l15) * 64 + (((mtl * 2 + (g >> 1)) ^ l7) * 8) + (g & 1) * 4;
#pragma unroll
  for (int kl = 0; kl < 2; ++kl)
    prd[kl] = ((kl * 4 + g) ^ l7) * 8; // + row*64 added per qs

  // prologue: stage K,V tile 0 into buf 0
#pragma unroll
  for (int p = 0; p < 2; ++p) {
    GLL16(Kgs + (size_t)(p * 32) * Dh, Ksh + p * 2048 + tid * 8);
    GLL16(Vgs + (size_t)(p * 32) * Pseq, Vsh + p * 2048 + tid * 8);
  }

  for (int j = 0; j < njt; ++j) {
    int buf = j & 1;
    __syncthreads(); // tile j staged; buf^1 reads (iter j-1) complete
    if (j + 1 < njt) {
      const bf16* Kg2 = Kgs + (size_t)((j + 1) * 64) * Dh;
      const bf16* Vg2 = Vgs + (j + 1) * 64;
      bf16* kd = Ksh + (buf ^ 1) * 4096 + tid * 8;
      bf16* vd = Vsh + (buf ^ 1) * 4096 + tid * 8;
#pragma unroll
      for (int p = 0; p < 2; ++p) {
        GLL16(Kg2 + (size_t)(p * 32) * Dh, kd + p * 2048);
        GLL16(Vg2 + (size_t)(p * 32) * Pseq, vd + p * 2048);
      }
    }
    // ---- S^T = K_j . Q^T; each kf feeds both q-subtiles ----
    f32x4 S[2][4];
#pragma unroll
    for (int qs = 0; qs < 2; ++qs)
#pragma unroll
      for (int mt = 0; mt < 4; ++mt) S[qs][mt] = zero;
    const bf16* Kr = Ksh + buf * 4096;
    const bf16* Vr = Vsh + buf * 4096;
#pragma unroll
    for (int ks = 0; ks < 2; ++ks) {
      int swz = ((ks * 4 + g) ^ l7) * 8;
#pragma unroll
      for (int mt = 0; mt < 4; ++mt) {
        bf16x8 kf = *(const bf16x8*)(Kr + (mt * 16 + l15) * 64 + swz);
        S[0][mt] = MFMA16(kf, qf[0][ks], S[0][mt]);
        S[1][mt] = MFMA16(kf, qf[1][ks], S[1][mt]);
      }
    }
    // ---- causal mask (diagonal spans last two kv tiles) ----
    if (j + 2 >= njt) {
#pragma unroll
      for (int qs = 0; qs < 2; ++qs) {
        int q = qw + qs * 16 + l15;
#pragma unroll
        for (int mt = 0; mt < 4; ++mt) {
          int kvb = j * 64 + mt * 16 + g * 4;
#pragma unroll
          for (int r = 0; r < 4; ++r)
            if (kvb + r > q) S[qs][mt][r] = BIG_NEG;
        }
      }
    }
    // ---- fixed-max softmax: p = 2^(S - M0); pack to P LDS ----
#pragma unroll
    for (int qs = 0; qs < 2; ++qs)
#pragma unroll
      for (int mt = 0; mt < 4; ++mt) {
        union { bf16 hh[4]; uint2 u; } pk;
#pragma unroll
        for (int r = 0; r < 4; ++r) {
          float p = __builtin_amdgcn_exp2f(S[qs][mt][r] - M0);
          lacc[qs][r] += p;
          pk.hh[r] = (bf16)p;
        }
        *(uint2*)(Pw + pwr[qs][mt]) = pk.u;
      }
    // ---- O += P . V; each vf feeds both q-subtiles ----
#pragma unroll
    for (int kl = 0; kl < 2; ++kl) {
      int swz = ((kl * 4 + g) ^ l7) * 8;
      bf16x8 pf0 = *(const bf16x8*)(Pw + l15 * 64 + prd[kl]);
      bf16x8 pf1 = *(const bf16x8*)(Pw + (16 + l15) * 64 + prd[kl]);
#pragma unroll
      for (int nt = 0; nt < 4; ++nt) {
        bf16x8 vf = *(const bf16x8*)(Vr + (nt * 16 + l15) * 64 + swz);
        O[0][nt] = MFMA16(pf0, vf, O[0][nt]);
        O[1][nt] = MFMA16(pf1, vf, O[1][nt]);
      }
    }
  }
  // ---- epilogue: reduce l across quads, O /= l, store Z [B,P,M] bf16 ----
#pragma unroll
  for (int qs = 0; qs < 2; ++qs) {
    float l_i = (lacc[qs][0] + lacc[qs][1]) + (lacc[qs][2] + lacc[qs][3]);
    l_i += __shfl_xor(l_i, 16);
    l_i += __shfl_xor(l_i, 32);
#pragma unroll
    for (int r = 0; r < 4; ++r) {
      float li = __shfl(l_i, g * 4 + r); // lane g*4+r holds sum for q-col g*4+r
      float inv = 1.0f / li;
      int q = qw + qs * 16 + g * 4 + r;
      size_t base = ((size_t)(b * Pseq + q)) * Mdim + h * Dh;
#pragma unroll
      for (int nt = 0; nt < 4; ++nt)
        Z[base + nt * 16 + l15] = (bf16)(O[qs][nt][r] * inv);
    }
  }
}

// ------- proj GEMM: Z [4096,1024] bf16 x Wproj^T -> out fp32, 64x64 tiles ----
__global__ __launch_bounds__(256) void k_proj(const bf16* __restrict__ Zb,
                                              const bf16* __restrict__ Wt,
                                              const float* __restrict__ bias,
                                              float* __restrict__ Out) {
  __shared__ __align__(16) bf16 Ash[64 * 64], Bsh[64 * 64]; // 16 KB
  int cb = blockIdx.x, rb = blockIdx.y;
  int row0 = rb * 64, col0 = cb * 64;
  f32x4 acc[2][2];
  const f32x4 zero = {0.f, 0.f, 0.f, 0.f};
#pragma unroll
  for (int mt = 0; mt < 2; ++mt)
#pragma unroll
    for (int nt = 0; nt < 2; ++nt) acc[mt][nt] = zero;
  gemm_core<64, 64>(Zb, Wt, Ash, Bsh, Mdim, row0, col0, acc);

  int lane = threadIdx.x & 63, w = threadIdx.x >> 6;
  int l15 = lane & 15, g = lane >> 4;
  int wm = w & 1, wn = w >> 1;
#pragma unroll
  for (int nt = 0; nt < 2; ++nt) {
    int col = col0 + wn * 32 + nt * 16 + l15;
    float bv = bias[col];
#pragma unroll
    for (int mt = 0; mt < 2; ++mt)
#pragma unroll
      for (int r = 0; r < 4; ++r) {
        int row = row0 + wm * 32 + mt * 16 + g * 4 + r;
        Out[(size_t)row * Mdim + col] = acc[mt][nt][r] + bv;
      }
  }
}

extern "C" void kernel_launch(void* const* d_in, const int* in_sizes, int n_in,
                              void* d_out, int out_size, void* d_ws, size_t ws_size,
                              hipStream_t stream) {
  const float* x = (const float*)d_in[0];
  const float* W_attn = (const float*)d_in[1];
  const float* b_attn = (const float*)d_in[2];
  const float* W_proj = (const float*)d_in[3];
  const float* b_proj = (const float*)d_in[4];
  float* out = (float*)d_out;

  bf16* Xb = (bf16*)d_ws;                    // 4096*1024
  bf16* Wat = Xb + (size_t)ROWS * Mdim;      // 3072*1024
  bf16* Wpt = Wat + (size_t)3 * Mdim * Mdim; // 1024*1024
  bf16* Qs = Wpt + (size_t)Mdim * Mdim;      // [B,H,P,D] (pre-scaled log2 domain)
  bf16* Ks = Qs + (size_t)ROWS * Mdim;       // [B,H,P,D]
  bf16* Vts = Ks + (size_t)ROWS * Mdim;      // [B,H,D,P]  (transposed V)
  bf16* Zb = Vts + (size_t)ROWS * Mdim;      // [B,P,M]

  k_pre<<<2048, 256, 0, stream>>>(x, Xb, W_attn, Wat, W_proj, Wpt);
  k_qkv<<<dim3(3 * Mdim / 128, ROWS / 128), 256, 0, stream>>>(Xb, Wat, b_attn, Qs, Ks, Vts);
  k_attn<<<dim3(Bsz * NH, Pseq / 128), 256, 0, stream>>>(Qs, Ks, Vts, Zb);
  k_proj<<<dim3(Mdim / 64, ROWS / 64), 256, 0, stream>>>(Zb, Wpt, b_proj, out);
}

// Round 11
// 173.524 us; speedup vs baseline: 1.0499x; 1.0499x over previous
//
#include <hip/hip_runtime.h>
#include <hip/hip_bf16.h>

typedef __bf16 bf16;
typedef __attribute__((ext_vector_type(8))) __bf16 bf16x8;
typedef __attribute__((ext_vector_type(4))) float f32x4;

#define MFMA16(a, b, c) __builtin_amdgcn_mfma_f32_16x16x32_bf16(a, b, c, 0, 0, 0)
// async global->LDS, 16B per lane; LDS dest = wave-uniform base + lane*16
#define GLL16(gp, lp)                                                          \
  __builtin_amdgcn_global_load_lds(                                            \
      (const __attribute__((address_space(1))) void*)(gp),                     \
      (__attribute__((address_space(3))) void*)(lp), 16, 0, 0)

constexpr int Bsz = 2, Pseq = 2048, Mdim = 1024, NH = 16, Dh = 64;
constexpr int ROWS = Bsz * Pseq; // 4096
constexpr float LOG2E = 1.4426950408889634f;
constexpr float BIG_NEG = -3.0e38f;
constexpr float M0 = 8.0f; // fixed softmax max (log2 domain); scores bounded << 8

// ---------------- fused pre-pass: x cvt + both weight transposes ------------
__global__ __launch_bounds__(256) void k_pre(const float* __restrict__ X,
                                             bf16* __restrict__ Xb,
                                             const float* __restrict__ Wa,
                                             bf16* __restrict__ Wat,
                                             const float* __restrict__ Wp,
                                             bf16* __restrict__ Wpt) {
  __shared__ __align__(16) bf16 tile[64][72];
  int blk = blockIdx.x;
  int t = threadIdx.x;
  if (blk < 1024) {
    const f32x4* X4 = (const f32x4*)X;
    int i0 = blk * 1024 + t; // 1024 blocks x 4 chunks x 256 threads = 2^20 float4s
#pragma unroll
    for (int c = 0; c < 4; ++c) {
      int i = i0 + c * 256;
      f32x4 v = X4[i];
      union { bf16 h[4]; uint2 u; } pk;
      pk.h[0] = (bf16)v[0]; pk.h[1] = (bf16)v[1];
      pk.h[2] = (bf16)v[2]; pk.h[3] = (bf16)v[3];
      ((uint2*)Xb)[i] = pk.u;
    }
    return;
  }
  const float* W; bf16* Wt; int Ndim, n0, k0;
  if (blk < 1792) {
    int bx = blk - 1024; // 48 n-tiles x 16 k-tiles
    W = Wa; Wt = Wat; Ndim = 3 * Mdim;
    n0 = (bx % 48) * 64; k0 = (bx / 48) * 64;
  } else {
    int bx = blk - 1792; // 16 x 16
    W = Wp; Wt = Wpt; Ndim = Mdim;
    n0 = (bx & 15) * 64; k0 = (bx >> 4) * 64;
  }
  int tc = t & 15, tr = t >> 4;
#pragma unroll
  for (int pass = 0; pass < 4; ++pass) {
    int r = tr + pass * 16;
    f32x4 v = *(const f32x4*)(W + (size_t)(k0 + r) * Ndim + n0 + tc * 4);
#pragma unroll
    for (int i = 0; i < 4; ++i) tile[tc * 4 + i][r] = (bf16)v[i];
  }
  __syncthreads();
#pragma unroll
  for (int pass = 0; pass < 4; ++pass) {
    int n = tr + pass * 16;
    union { bf16 h[4]; uint2 u; } pk;
#pragma unroll
    for (int i = 0; i < 4; ++i) pk.h[i] = tile[n][tc * 4 + i];
    *(uint2*)(Wt + (size_t)(n0 + n) * Mdim + k0 + tc * 4) = pk.u;
  }
}

// -------- r5-proven GEMM core, generalized: C(TM x TN) = A[M][K].Bt[N][K]^T --
// BK=64, single-buffered (measured best at 3-4 blocks/CU, K=1024: r5=44us vs
// BK=32=51us, dbuf=60us). 2x2 waves, wave covers TM/2 x TN/2. XOR-swizzled
// 16B granules (key row&7) -> staging + b128 reads conflict-free.
template <int TM, int TN>
__device__ __forceinline__ void gemm_core(const bf16* __restrict__ A,
                                          const bf16* __restrict__ Bt,
                                          bf16* Ash, bf16* Bsh, int K,
                                          int row0, int col0,
                                          f32x4 (&acc)[TM / 32][TN / 32]) {
  constexpr int MT = TM / 32, NT = TN / 32;
  int tid = threadIdx.x;
  int lane = tid & 63, w = tid >> 6;
  int l15 = lane & 15, g = lane >> 4, l7 = lane & 7, l8 = lane >> 3;
  int wm = w & 1, wn = w >> 1;
  const bf16* Ag = A + (size_t)(row0 + w * 8 + l8) * K + (l7 ^ l8) * 8;
  const bf16* Bg = Bt + (size_t)(col0 + w * 8 + l8) * K + (l7 ^ l8) * 8;
  bf16* Asb = Ash + w * 512;
  bf16* Bsb = Bsh + w * 512;
  for (int k0 = 0; k0 < K; k0 += 64) {
#pragma unroll
    for (int p = 0; p < MT; ++p)
      GLL16(Ag + (size_t)(p * 32) * K + k0, Asb + p * 2048);
#pragma unroll
    for (int p = 0; p < NT; ++p)
      GLL16(Bg + (size_t)(p * 32) * K + k0, Bsb + p * 2048);
    __syncthreads();
#pragma unroll
    for (int ks = 0; ks < 2; ++ks) {
      int swz = ((ks * 4 + g) ^ l7) * 8;
      bf16x8 af[MT], bfr[NT];
#pragma unroll
      for (int mt = 0; mt < MT; ++mt)
        af[mt] = *(const bf16x8*)(Ash + (wm * (TM / 2) + mt * 16 + l15) * 64 + swz);
#pragma unroll
      for (int nt = 0; nt < NT; ++nt)
        bfr[nt] = *(const bf16x8*)(Bsh + (wn * (TN / 2) + nt * 16 + l15) * 64 + swz);
#pragma unroll
      for (int mt = 0; mt < MT; ++mt)
#pragma unroll
        for (int nt = 0; nt < NT; ++nt)
          acc[mt][nt] = MFMA16(af[mt], bfr[nt], acc[mt][nt]);
    }
    __syncthreads();
  }
}

// ---------------- QKV GEMM -> Q (pre-scaled by log2e/8), K [B,H,P,D]; V [B,H,D,P]
__global__ __launch_bounds__(256) void k_qkv(const bf16* __restrict__ Xb,
                                             const bf16* __restrict__ Wt,
                                             const float* __restrict__ bias,
                                             bf16* __restrict__ Qo,
                                             bf16* __restrict__ Ko,
                                             bf16* __restrict__ Vto) {
  __shared__ __align__(16) bf16 Ash[128 * 64], Bsh[128 * 64]; // 32 KB
  int cb = blockIdx.x, rb = blockIdx.y;
  int row0 = rb * 128, col0 = cb * 128;
  f32x4 acc[4][4];
  const f32x4 zero = {0.f, 0.f, 0.f, 0.f};
#pragma unroll
  for (int mt = 0; mt < 4; ++mt)
#pragma unroll
    for (int nt = 0; nt < 4; ++nt) acc[mt][nt] = zero;
  gemm_core<128, 128>(Xb, Wt, Ash, Bsh, Mdim, row0, col0, acc);

  int lane = threadIdx.x & 63, w = threadIdx.x >> 6;
  int l15 = lane & 15, g = lane >> 4;
  int wm = w & 1, wn = w >> 1;
  int sec = cb >> 3; // 0=q 1=k 2=v (uniform per block)
  if (sec < 2) {
    bf16* out = sec == 0 ? Qo : Ko;
    float scale = sec == 0 ? (0.125f * LOG2E) : 1.0f; // q/sqrt(64), log2 domain
#pragma unroll
    for (int nt = 0; nt < 4; ++nt) {
      int col = col0 + wn * 64 + nt * 16 + l15;
      int cm = col & 1023;
      int h = cm >> 6, d = cm & 63;
      float bv = bias[col];
#pragma unroll
      for (int mt = 0; mt < 4; ++mt)
#pragma unroll
        for (int r = 0; r < 4; ++r) {
          int row = row0 + wm * 64 + mt * 16 + g * 4 + r;
          int b = row >> 11, p = row & 2047;
          out[(size_t)((b * NH + h) * Pseq + p) * Dh + d] =
              (bf16)((acc[mt][nt][r] + bv) * scale);
        }
    }
  } else {
#pragma unroll
    for (int nt = 0; nt < 4; ++nt) {
      int col = col0 + wn * 64 + nt * 16 + l15;
      int cm = col & 1023;
      int h = cm >> 6, d = cm & 63;
      float bv = bias[col];
#pragma unroll
      for (int mt = 0; mt < 4; ++mt) {
        int row = row0 + wm * 64 + mt * 16 + g * 4;
        int b = row >> 11, p = row & 2047;
        union { bf16 hh[4]; uint2 u; } pk;
#pragma unroll
        for (int r = 0; r < 4; ++r) pk.hh[r] = (bf16)(acc[mt][nt][r] + bv);
        *(uint2*)(Vto + ((size_t)((b * NH + h) * Dh + d)) * Pseq + p) = pk.u;
      }
    }
  }
}

// ---------------- causal flash attention (r5-proven, session-best) -----------
// Q,K [B,H,P,D] (Q pre-scaled log2e/8); Vt [B,H,D,P]; Z [B,P,M].
// 64-q tiles (16 q/wave), 64-kv tiles, K+V double-buffered LDS staging via
// global_load_lds, fixed-max softmax, per-wave swizzled P. 40KB LDS ->
// 4 blocks/CU; 1024 blocks all co-resident; per-CU qt sums balanced (=66)
// under stride-256 round-robin via y<16?y:47-y mapping.
__global__ __launch_bounds__(256, 4) void k_attn(const bf16* __restrict__ Q,
                                                 const bf16* __restrict__ K,
                                                 const bf16* __restrict__ Vt,
                                                 bf16* __restrict__ Z) {
  __shared__ __align__(16) bf16 Ksh[2 * 64 * 64]; // 16 KB dbuf [buf][kv][d]
  __shared__ __align__(16) bf16 Vsh[2 * 64 * 64]; // 16 KB dbuf [buf][d][kv]
  __shared__ __align__(16) bf16 Pb[4 * 16 * 64];  // 8 KB, per-wave P
  int bh = blockIdx.x;
  int y = blockIdx.y;
  int qt = (y < 16) ? y : 47 - y; // per-CU heavy+light pairing
  int b = bh >> 4, h = bh & 15;
  const bf16* Qb = Q + (size_t)bh * Pseq * Dh;
  const bf16* Kb = K + (size_t)bh * Pseq * Dh;
  const bf16* Vb = Vt + (size_t)bh * Dh * Pseq;
  int tid = threadIdx.x;
  int lane = tid & 63, w = tid >> 6;
  int l15 = lane & 15, g = lane >> 4, l7 = lane & 7;
  int q0 = qt * 64;
  int njt = qt + 1; // kv64 tiles covering [0, 64*(qt+1))

  bf16x8 qf[2];
#pragma unroll
  for (int ks = 0; ks < 2; ++ks)
    qf[ks] = *(const bf16x8*)(Qb + (size_t)(q0 + w * 16 + l15) * Dh + ks * 32 + g * 8);

  f32x4 O[4];
  const f32x4 zero = {0.f, 0.f, 0.f, 0.f};
#pragma unroll
  for (int nt = 0; nt < 4; ++nt) O[nt] = zero;
  float lacc[4] = {0.f, 0.f, 0.f, 0.f};

  int srow = tid >> 3;
  int sgr = (tid & 7) ^ (srow & 7);
  const bf16* Kgs = Kb + (size_t)srow * Dh + sgr * 8;
  const bf16* Vgs = Vb + (size_t)srow * Pseq + sgr * 8;
  bf16* Pw = Pb + w * 1024;
  int pwr[4], prd[2];
#pragma unroll
  for (int mtl = 0; mtl < 4; ++mtl)
    pwr[mtl] = l15 * 64 + (((mtl * 2 + (g >> 1)) ^ l7) * 8) + (g & 1) * 4;
#pragma unroll
  for (int kl = 0; kl < 2; ++kl)
    prd[kl] = l15 * 64 + (((kl * 4 + g) ^ l7) * 8);

#pragma unroll
  for (int p = 0; p < 2; ++p) {
    GLL16(Kgs + (size_t)(p * 32) * Dh, Ksh + p * 2048 + tid * 8);
    GLL16(Vgs + (size_t)(p * 32) * Pseq, Vsh + p * 2048 + tid * 8);
  }

  for (int j = 0; j < njt; ++j) {
    int buf = j & 1;
    __syncthreads();
    if (j + 1 < njt) {
      const bf16* Kg2 = Kgs + (size_t)((j + 1) * 64) * Dh;
      const bf16* Vg2 = Vgs + (j + 1) * 64;
      bf16* kd = Ksh + (buf ^ 1) * 4096 + tid * 8;
      bf16* vd = Vsh + (buf ^ 1) * 4096 + tid * 8;
#pragma unroll
      for (int p = 0; p < 2; ++p) {
        GLL16(Kg2 + (size_t)(p * 32) * Dh, kd + p * 2048);
        GLL16(Vg2 + (size_t)(p * 32) * Pseq, vd + p * 2048);
      }
    }
    f32x4 S[4];
#pragma unroll
    for (int mt = 0; mt < 4; ++mt) S[mt] = zero;
    const bf16* Kr = Ksh + buf * 4096;
    const bf16* Vr = Vsh + buf * 4096;
#pragma unroll
    for (int ks = 0; ks < 2; ++ks) {
      int swz = ((ks * 4 + g) ^ l7) * 8;
#pragma unroll
      for (int mt = 0; mt < 4; ++mt) {
        bf16x8 kf = *(const bf16x8*)(Kr + (mt * 16 + l15) * 64 + swz);
        S[mt] = MFMA16(kf, qf[ks], S[mt]);
      }
    }
    if (j == njt - 1) {
      int q = q0 + w * 16 + l15;
#pragma unroll
      for (int mt = 0; mt < 4; ++mt) {
        int kvb = j * 64 + mt * 16 + g * 4;
#pragma unroll
        for (int r = 0; r < 4; ++r)
          if (kvb + r > q) S[mt][r] = BIG_NEG;
      }
    }
#pragma unroll
    for (int mt = 0; mt < 4; ++mt) {
      union { bf16 hh[4]; uint2 u; } pk;
#pragma unroll
      for (int r = 0; r < 4; ++r) {
        float p = __builtin_amdgcn_exp2f(S[mt][r] - M0);
        lacc[r] += p;
        pk.hh[r] = (bf16)p;
      }
      *(uint2*)(Pw + pwr[mt]) = pk.u;
    }
#pragma unroll
    for (int kl = 0; kl < 2; ++kl) {
      bf16x8 pf = *(const bf16x8*)(Pw + prd[kl]);
      int swz = ((kl * 4 + g) ^ l7) * 8;
#pragma unroll
      for (int nt = 0; nt < 4; ++nt) {
        bf16x8 vf = *(const bf16x8*)(Vr + (nt * 16 + l15) * 64 + swz);
        O[nt] = MFMA16(pf, vf, O[nt]);
      }
    }
  }
  float l_i = (lacc[0] + lacc[1]) + (lacc[2] + lacc[3]);
  l_i += __shfl_xor(l_i, 16);
  l_i += __shfl_xor(l_i, 32);
#pragma unroll
  for (int r = 0; r < 4; ++r) {
    float li = __shfl(l_i, g * 4 + r);
    float inv = 1.0f / li;
    int q = q0 + w * 16 + g * 4 + r;
    size_t base = ((size_t)(b * Pseq + q)) * Mdim + h * Dh;
#pragma unroll
    for (int nt = 0; nt < 4; ++nt)
      Z[base + nt * 16 + l15] = (bf16)(O[nt][r] * inv);
  }
}

// ------- proj GEMM: Z [4096,1024] bf16 x Wproj^T -> out fp32, 64x64 tiles ----
// 1024 blocks = 4 blocks/CU.
__global__ __launch_bounds__(256) void k_proj(const bf16* __restrict__ Zb,
                                              const bf16* __restrict__ Wt,
                                              const float* __restrict__ bias,
                                              float* __restrict__ Out) {
  __shared__ __align__(16) bf16 Ash[64 * 64], Bsh[64 * 64]; // 16 KB
  int cb = blockIdx.x, rb = blockIdx.y;
  int row0 = rb * 64, col0 = cb * 64;
  f32x4 acc[2][2];
  const f32x4 zero = {0.f, 0.f, 0.f, 0.f};
#pragma unroll
  for (int mt = 0; mt < 2; ++mt)
#pragma unroll
    for (int nt = 0; nt < 2; ++nt) acc[mt][nt] = zero;
  gemm_core<64, 64>(Zb, Wt, Ash, Bsh, Mdim, row0, col0, acc);

  int lane = threadIdx.x & 63, w = threadIdx.x >> 6;
  int l15 = lane & 15, g = lane >> 4;
  int wm = w & 1, wn = w >> 1;
#pragma unroll
  for (int nt = 0; nt < 2; ++nt) {
    int col = col0 + wn * 32 + nt * 16 + l15;
    float bv = bias[col];
#pragma unroll
    for (int mt = 0; mt < 2; ++mt)
#pragma unroll
      for (int r = 0; r < 4; ++r) {
        int row = row0 + wm * 32 + mt * 16 + g * 4 + r;
        Out[(size_t)row * Mdim + col] = acc[mt][nt][r] + bv;
      }
  }
}

extern "C" void kernel_launch(void* const* d_in, const int* in_sizes, int n_in,
                              void* d_out, int out_size, void* d_ws, size_t ws_size,
                              hipStream_t stream) {
  const float* x = (const float*)d_in[0];
  const float* W_attn = (const float*)d_in[1];
  const float* b_attn = (const float*)d_in[2];
  const float* W_proj = (const float*)d_in[3];
  const float* b_proj = (const float*)d_in[4];
  float* out = (float*)d_out;

  bf16* Xb = (bf16*)d_ws;                    // 4096*1024
  bf16* Wat = Xb + (size_t)ROWS * Mdim;      // 3072*1024
  bf16* Wpt = Wat + (size_t)3 * Mdim * Mdim; // 1024*1024
  bf16* Qs = Wpt + (size_t)Mdim * Mdim;      // [B,H,P,D] (pre-scaled log2 domain)
  bf16* Ks = Qs + (size_t)ROWS * Mdim;       // [B,H,P,D]
  bf16* Vts = Ks + (size_t)ROWS * Mdim;      // [B,H,D,P]  (transposed V)
  bf16* Zb = Vts + (size_t)ROWS * Mdim;      // [B,P,M]

  k_pre<<<2048, 256, 0, stream>>>(x, Xb, W_attn, Wat, W_proj, Wpt);
  k_qkv<<<dim3(3 * Mdim / 128, ROWS / 128), 256, 0, stream>>>(Xb, Wat, b_attn, Qs, Ks, Vts);
  k_attn<<<dim3(Bsz * NH, Pseq / 64), 256, 0, stream>>>(Qs, Ks, Vts, Zb);
  k_proj<<<dim3(Mdim / 64, ROWS / 64), 256, 0, stream>>>(Zb, Wpt, b_proj, out);
}

// Round 12
// 162.346 us; speedup vs baseline: 1.1222x; 1.0689x over previous
//
#include <hip/hip_runtime.h>
#include <hip/hip_bf16.h>

typedef __bf16 bf16;
typedef __attribute__((ext_vector_type(8))) __bf16 bf16x8;
typedef __attribute__((ext_vector_type(4))) float f32x4;

#define MFMA16(a, b, c) __builtin_amdgcn_mfma_f32_16x16x32_bf16(a, b, c, 0, 0, 0)
// async global->LDS, 16B per lane; LDS dest = wave-uniform base + lane*16
#define GLL16(gp, lp)                                                          \
  __builtin_amdgcn_global_load_lds(                                            \
      (const __attribute__((address_space(1))) void*)(gp),                     \
      (__attribute__((address_space(3))) void*)(lp), 16, 0, 0)

constexpr int Bsz = 2, Pseq = 2048, Mdim = 1024, NH = 16, Dh = 64;
constexpr int ROWS = Bsz * Pseq; // 4096
constexpr float LOG2E = 1.4426950408889634f;
constexpr float BIG_NEG = -3.0e38f;
constexpr float M0 = 8.0f; // fixed softmax max (log2 domain); scores bounded << 8

// ---------------- fused pre-pass: x cvt + both weight transposes ------------
__global__ __launch_bounds__(256) void k_pre(const float* __restrict__ X,
                                             bf16* __restrict__ Xb,
                                             const float* __restrict__ Wa,
                                             bf16* __restrict__ Wat,
                                             const float* __restrict__ Wp,
                                             bf16* __restrict__ Wpt) {
  __shared__ __align__(16) bf16 tile[64][72];
  int blk = blockIdx.x;
  int t = threadIdx.x;
  if (blk < 1024) {
    const f32x4* X4 = (const f32x4*)X;
    int i0 = blk * 1024 + t; // 1024 blocks x 4 chunks x 256 threads = 2^20 float4s
#pragma unroll
    for (int c = 0; c < 4; ++c) {
      int i = i0 + c * 256;
      f32x4 v = X4[i];
      union { bf16 h[4]; uint2 u; } pk;
      pk.h[0] = (bf16)v[0]; pk.h[1] = (bf16)v[1];
      pk.h[2] = (bf16)v[2]; pk.h[3] = (bf16)v[3];
      ((uint2*)Xb)[i] = pk.u;
    }
    return;
  }
  const float* W; bf16* Wt; int Ndim, n0, k0;
  if (blk < 1792) {
    int bx = blk - 1024; // 48 n-tiles x 16 k-tiles
    W = Wa; Wt = Wat; Ndim = 3 * Mdim;
    n0 = (bx % 48) * 64; k0 = (bx / 48) * 64;
  } else {
    int bx = blk - 1792; // 16 x 16
    W = Wp; Wt = Wpt; Ndim = Mdim;
    n0 = (bx & 15) * 64; k0 = (bx >> 4) * 64;
  }
  int tc = t & 15, tr = t >> 4;
#pragma unroll
  for (int pass = 0; pass < 4; ++pass) {
    int r = tr + pass * 16;
    f32x4 v = *(const f32x4*)(W + (size_t)(k0 + r) * Ndim + n0 + tc * 4);
#pragma unroll
    for (int i = 0; i < 4; ++i) tile[tc * 4 + i][r] = (bf16)v[i];
  }
  __syncthreads();
#pragma unroll
  for (int pass = 0; pass < 4; ++pass) {
    int n = tr + pass * 16;
    union { bf16 h[4]; uint2 u; } pk;
#pragma unroll
    for (int i = 0; i < 4; ++i) pk.h[i] = tile[n][tc * 4 + i];
    *(uint2*)(Wt + (size_t)(n0 + n) * Mdim + k0 + tc * 4) = pk.u;
  }
}

// -------- r5-proven GEMM core (4 waves): C(TM x TN) = A[M][K].Bt[N][K]^T ----
template <int TM, int TN>
__device__ __forceinline__ void gemm_core(const bf16* __restrict__ A,
                                          const bf16* __restrict__ Bt,
                                          bf16* Ash, bf16* Bsh, int K,
                                          int row0, int col0,
                                          f32x4 (&acc)[TM / 32][TN / 32]) {
  constexpr int MT = TM / 32, NT = TN / 32;
  int tid = threadIdx.x;
  int lane = tid & 63, w = tid >> 6;
  int l15 = lane & 15, g = lane >> 4, l7 = lane & 7, l8 = lane >> 3;
  int wm = w & 1, wn = w >> 1;
  const bf16* Ag = A + (size_t)(row0 + w * 8 + l8) * K + (l7 ^ l8) * 8;
  const bf16* Bg = Bt + (size_t)(col0 + w * 8 + l8) * K + (l7 ^ l8) * 8;
  bf16* Asb = Ash + w * 512;
  bf16* Bsb = Bsh + w * 512;
  for (int k0 = 0; k0 < K; k0 += 64) {
#pragma unroll
    for (int p = 0; p < MT; ++p)
      GLL16(Ag + (size_t)(p * 32) * K + k0, Asb + p * 2048);
#pragma unroll
    for (int p = 0; p < NT; ++p)
      GLL16(Bg + (size_t)(p * 32) * K + k0, Bsb + p * 2048);
    __syncthreads();
#pragma unroll
    for (int ks = 0; ks < 2; ++ks) {
      int swz = ((ks * 4 + g) ^ l7) * 8;
      bf16x8 af[MT], bfr[NT];
#pragma unroll
      for (int mt = 0; mt < MT; ++mt)
        af[mt] = *(const bf16x8*)(Ash + (wm * (TM / 2) + mt * 16 + l15) * 64 + swz);
#pragma unroll
      for (int nt = 0; nt < NT; ++nt)
        bfr[nt] = *(const bf16x8*)(Bsh + (wn * (TN / 2) + nt * 16 + l15) * 64 + swz);
#pragma unroll
      for (int mt = 0; mt < MT; ++mt)
#pragma unroll
        for (int nt = 0; nt < NT; ++nt)
          acc[mt][nt] = MFMA16(af[mt], bfr[nt], acc[mt][nt]);
    }
    __syncthreads();
  }
}

// ------- QKV GEMM, 8-wave blocks: 128x128 tile, 24 waves/CU at 768 blocks ----
// Same LDS layout invariant as gemm_core (elem(row,kg) @ row*64+(kg^(row&7))*8)
// and same proven fragment swizzle; wave covers 64x32, acc[4][2].
__global__ __launch_bounds__(512) void k_qkv(const bf16* __restrict__ Xb,
                                             const bf16* __restrict__ Wt,
                                             const float* __restrict__ bias,
                                             bf16* __restrict__ Qo,
                                             bf16* __restrict__ Ko,
                                             bf16* __restrict__ Vto) {
  __shared__ __align__(16) bf16 Ash[128 * 64], Bsh[128 * 64]; // 32 KB
  int cb = blockIdx.x, rb = blockIdx.y;
  int row0 = rb * 128, col0 = cb * 128;
  int tid = threadIdx.x;
  int lane = tid & 63, w = tid >> 6; // w in 0..7
  int l15 = lane & 15, g = lane >> 4, l7 = lane & 7;
  int wm = w & 1, wn = w >> 1; // row half 64, col quarter 32
  int sr = tid >> 3;           // 0..63: staging row within pass
  int sc = (tid & 7) ^ (sr & 7);
  const bf16* Ag = Xb + (size_t)(row0 + sr) * Mdim + sc * 8;
  const bf16* Bg = Wt + (size_t)(col0 + sr) * Mdim + sc * 8;

  f32x4 acc[4][2];
  const f32x4 zero = {0.f, 0.f, 0.f, 0.f};
#pragma unroll
  for (int mt = 0; mt < 4; ++mt)
#pragma unroll
    for (int nt = 0; nt < 2; ++nt) acc[mt][nt] = zero;

  for (int k0 = 0; k0 < Mdim; k0 += 64) {
    GLL16(Ag + k0, Ash + tid * 8);
    GLL16(Ag + (size_t)64 * Mdim + k0, Ash + 4096 + tid * 8);
    GLL16(Bg + k0, Bsh + tid * 8);
    GLL16(Bg + (size_t)64 * Mdim + k0, Bsh + 4096 + tid * 8);
    __syncthreads();
#pragma unroll
    for (int ks = 0; ks < 2; ++ks) {
      int swz = ((ks * 4 + g) ^ l7) * 8;
      bf16x8 af[4], bfr[2];
#pragma unroll
      for (int mt = 0; mt < 4; ++mt)
        af[mt] = *(const bf16x8*)(Ash + (wm * 64 + mt * 16 + l15) * 64 + swz);
#pragma unroll
      for (int nt = 0; nt < 2; ++nt)
        bfr[nt] = *(const bf16x8*)(Bsh + (wn * 32 + nt * 16 + l15) * 64 + swz);
#pragma unroll
      for (int mt = 0; mt < 4; ++mt)
#pragma unroll
        for (int nt = 0; nt < 2; ++nt)
          acc[mt][nt] = MFMA16(af[mt], bfr[nt], acc[mt][nt]);
    }
    __syncthreads();
  }

  int sec = cb >> 3; // 0=q 1=k 2=v (uniform per block)
  if (sec < 2) {
    bf16* out = sec == 0 ? Qo : Ko;
    float scale = sec == 0 ? (0.125f * LOG2E) : 1.0f; // q/sqrt(64), log2 domain
#pragma unroll
    for (int nt = 0; nt < 2; ++nt) {
      int col = col0 + wn * 32 + nt * 16 + l15;
      int cm = col & 1023;
      int h = cm >> 6, d = cm & 63;
      float bv = bias[col];
#pragma unroll
      for (int mt = 0; mt < 4; ++mt)
#pragma unroll
        for (int r = 0; r < 4; ++r) {
          int row = row0 + wm * 64 + mt * 16 + g * 4 + r;
          int b = row >> 11, p = row & 2047;
          out[(size_t)((b * NH + h) * Pseq + p) * Dh + d] =
              (bf16)((acc[mt][nt][r] + bv) * scale);
        }
    }
  } else {
#pragma unroll
    for (int nt = 0; nt < 2; ++nt) {
      int col = col0 + wn * 32 + nt * 16 + l15;
      int cm = col & 1023;
      int h = cm >> 6, d = cm & 63;
      float bv = bias[col];
#pragma unroll
      for (int mt = 0; mt < 4; ++mt) {
        int row = row0 + wm * 64 + mt * 16 + g * 4;
        int b = row >> 11, p = row & 2047;
        union { bf16 hh[4]; uint2 u; } pk;
#pragma unroll
        for (int r = 0; r < 4; ++r) pk.hh[r] = (bf16)(acc[mt][nt][r] + bv);
        *(uint2*)(Vto + ((size_t)((b * NH + h) * Dh + d)) * Pseq + p) = pk.u;
      }
    }
  }
}

// ---------------- causal flash attention (r5-proven, session-best) -----------
__global__ __launch_bounds__(256, 4) void k_attn(const bf16* __restrict__ Q,
                                                 const bf16* __restrict__ K,
                                                 const bf16* __restrict__ Vt,
                                                 bf16* __restrict__ Z) {
  __shared__ __align__(16) bf16 Ksh[2 * 64 * 64]; // 16 KB dbuf [buf][kv][d]
  __shared__ __align__(16) bf16 Vsh[2 * 64 * 64]; // 16 KB dbuf [buf][d][kv]
  __shared__ __align__(16) bf16 Pb[4 * 16 * 64];  // 8 KB, per-wave P
  int bh = blockIdx.x;
  int y = blockIdx.y;
  int qt = (y < 16) ? y : 47 - y; // per-CU heavy+light pairing
  int b = bh >> 4, h = bh & 15;
  const bf16* Qb = Q + (size_t)bh * Pseq * Dh;
  const bf16* Kb = K + (size_t)bh * Pseq * Dh;
  const bf16* Vb = Vt + (size_t)bh * Dh * Pseq;
  int tid = threadIdx.x;
  int lane = tid & 63, w = tid >> 6;
  int l15 = lane & 15, g = lane >> 4, l7 = lane & 7;
  int q0 = qt * 64;
  int njt = qt + 1; // kv64 tiles covering [0, 64*(qt+1))

  bf16x8 qf[2];
#pragma unroll
  for (int ks = 0; ks < 2; ++ks)
    qf[ks] = *(const bf16x8*)(Qb + (size_t)(q0 + w * 16 + l15) * Dh + ks * 32 + g * 8);

  f32x4 O[4];
  const f32x4 zero = {0.f, 0.f, 0.f, 0.f};
#pragma unroll
  for (int nt = 0; nt < 4; ++nt) O[nt] = zero;
  float lacc[4] = {0.f, 0.f, 0.f, 0.f};

  int srow = tid >> 3;
  int sgr = (tid & 7) ^ (srow & 7);
  const bf16* Kgs = Kb + (size_t)srow * Dh + sgr * 8;
  const bf16* Vgs = Vb + (size_t)srow * Pseq + sgr * 8;
  bf16* Pw = Pb + w * 1024;
  int pwr[4], prd[2];
#pragma unroll
  for (int mtl = 0; mtl < 4; ++mtl)
    pwr[mtl] = l15 * 64 + (((mtl * 2 + (g >> 1)) ^ l7) * 8) + (g & 1) * 4;
#pragma unroll
  for (int kl = 0; kl < 2; ++kl)
    prd[kl] = l15 * 64 + (((kl * 4 + g) ^ l7) * 8);

#pragma unroll
  for (int p = 0; p < 2; ++p) {
    GLL16(Kgs + (size_t)(p * 32) * Dh, Ksh + p * 2048 + tid * 8);
    GLL16(Vgs + (size_t)(p * 32) * Pseq, Vsh + p * 2048 + tid * 8);
  }

  for (int j = 0; j < njt; ++j) {
    int buf = j & 1;
    __syncthreads();
    if (j + 1 < njt) {
      const bf16* Kg2 = Kgs + (size_t)((j + 1) * 64) * Dh;
      const bf16* Vg2 = Vgs + (j + 1) * 64;
      bf16* kd = Ksh + (buf ^ 1) * 4096 + tid * 8;
      bf16* vd = Vsh + (buf ^ 1) * 4096 + tid * 8;
#pragma unroll
      for (int p = 0; p < 2; ++p) {
        GLL16(Kg2 + (size_t)(p * 32) * Dh, kd + p * 2048);
        GLL16(Vg2 + (size_t)(p * 32) * Pseq, vd + p * 2048);
      }
    }
    f32x4 S[4];
#pragma unroll
    for (int mt = 0; mt < 4; ++mt) S[mt] = zero;
    const bf16* Kr = Ksh + buf * 4096;
    const bf16* Vr = Vsh + buf * 4096;
#pragma unroll
    for (int ks = 0; ks < 2; ++ks) {
      int swz = ((ks * 4 + g) ^ l7) * 8;
#pragma unroll
      for (int mt = 0; mt < 4; ++mt) {
        bf16x8 kf = *(const bf16x8*)(Kr + (mt * 16 + l15) * 64 + swz);
        S[mt] = MFMA16(kf, qf[ks], S[mt]);
      }
    }
    if (j == njt - 1) {
      int q = q0 + w * 16 + l15;
#pragma unroll
      for (int mt = 0; mt < 4; ++mt) {
        int kvb = j * 64 + mt * 16 + g * 4;
#pragma unroll
        for (int r = 0; r < 4; ++r)
          if (kvb + r > q) S[mt][r] = BIG_NEG;
      }
    }
#pragma unroll
    for (int mt = 0; mt < 4; ++mt) {
      union { bf16 hh[4]; uint2 u; } pk;
#pragma unroll
      for (int r = 0; r < 4; ++r) {
        float p = __builtin_amdgcn_exp2f(S[mt][r] - M0);
        lacc[r] += p;
        pk.hh[r] = (bf16)p;
      }
      *(uint2*)(Pw + pwr[mt]) = pk.u;
    }
#pragma unroll
    for (int kl = 0; kl < 2; ++kl) {
      bf16x8 pf = *(const bf16x8*)(Pw + prd[kl]);
      int swz = ((kl * 4 + g) ^ l7) * 8;
#pragma unroll
      for (int nt = 0; nt < 4; ++nt) {
        bf16x8 vf = *(const bf16x8*)(Vr + (nt * 16 + l15) * 64 + swz);
        O[nt] = MFMA16(pf, vf, O[nt]);
      }
    }
  }
  float l_i = (lacc[0] + lacc[1]) + (lacc[2] + lacc[3]);
  l_i += __shfl_xor(l_i, 16);
  l_i += __shfl_xor(l_i, 32);
#pragma unroll
  for (int r = 0; r < 4; ++r) {
    float li = __shfl(l_i, g * 4 + r);
    float inv = 1.0f / li;
    int q = q0 + w * 16 + g * 4 + r;
    size_t base = ((size_t)(b * Pseq + q)) * Mdim + h * Dh;
#pragma unroll
    for (int nt = 0; nt < 4; ++nt)
      Z[base + nt * 16 + l15] = (bf16)(O[nt][r] * inv);
  }
}

// ------- proj GEMM: Z [4096,1024] bf16 x Wproj^T -> out fp32, 64x64 tiles ----
__global__ __launch_bounds__(256) void k_proj(const bf16* __restrict__ Zb,
                                              const bf16* __restrict__ Wt,
                                              const float* __restrict__ bias,
                                              float* __restrict__ Out) {
  __shared__ __align__(16) bf16 Ash[64 * 64], Bsh[64 * 64]; // 16 KB
  int cb = blockIdx.x, rb = blockIdx.y;
  int row0 = rb * 64, col0 = cb * 64;
  f32x4 acc[2][2];
  const f32x4 zero = {0.f, 0.f, 0.f, 0.f};
#pragma unroll
  for (int mt = 0; mt < 2; ++mt)
#pragma unroll
    for (int nt = 0; nt < 2; ++nt) acc[mt][nt] = zero;
  gemm_core<64, 64>(Zb, Wt, Ash, Bsh, Mdim, row0, col0, acc);

  int lane = threadIdx.x & 63, w = threadIdx.x >> 6;
  int l15 = lane & 15, g = lane >> 4;
  int wm = w & 1, wn = w >> 1;
#pragma unroll
  for (int nt = 0; nt < 2; ++nt) {
    int col = col0 + wn * 32 + nt * 16 + l15;
    float bv = bias[col];
#pragma unroll
    for (int mt = 0; mt < 2; ++mt)
#pragma unroll
      for (int r = 0; r < 4; ++r) {
        int row = row0 + wm * 32 + mt * 16 + g * 4 + r;
        Out[(size_t)row * Mdim + col] = acc[mt][nt][r] + bv;
      }
  }
}

extern "C" void kernel_launch(void* const* d_in, const int* in_sizes, int n_in,
                              void* d_out, int out_size, void* d_ws, size_t ws_size,
                              hipStream_t stream) {
  const float* x = (const float*)d_in[0];
  const float* W_attn = (const float*)d_in[1];
  const float* b_attn = (const float*)d_in[2];
  const float* W_proj = (const float*)d_in[3];
  const float* b_proj = (const float*)d_in[4];
  float* out = (float*)d_out;

  bf16* Xb = (bf16*)d_ws;                    // 4096*1024
  bf16* Wat = Xb + (size_t)ROWS * Mdim;      // 3072*1024
  bf16* Wpt = Wat + (size_t)3 * Mdim * Mdim; // 1024*1024
  bf16* Qs = Wpt + (size_t)Mdim * Mdim;      // [B,H,P,D] (pre-scaled log2 domain)
  bf16* Ks = Qs + (size_t)ROWS * Mdim;       // [B,H,P,D]
  bf16* Vts = Ks + (size_t)ROWS * Mdim;      // [B,H,D,P]  (transposed V)
  bf16* Zb = Vts + (size_t)ROWS * Mdim;      // [B,P,M]

  k_pre<<<2048, 256, 0, stream>>>(x, Xb, W_attn, Wat, W_proj, Wpt);
  k_qkv<<<dim3(3 * Mdim / 128, ROWS / 128), 512, 0, stream>>>(Xb, Wat, b_attn, Qs, Ks, Vts);
  k_attn<<<dim3(Bsz * NH, Pseq / 64), 256, 0, stream>>>(Qs, Ks, Vts, Zb);
  k_proj<<<dim3(Mdim / 64, ROWS / 64), 256, 0, stream>>>(Zb, Wpt, b_proj, out);
}